// Round 1
// baseline (139.795 us; speedup 1.0000x reference)
//
#include <hip/hip_runtime.h>
#include <math.h>

#define B 8
#define NPTS 4096
#define SPLITS 8        // ref splits per direction
#define REFS 512        // refs per split  (SPLITS*REFS == NPTS)
#define QPB 512         // query points per block (2 per thread)
#define THREADS 256

// -------- K1: split-partial chamfer mins --------------------------------
// grid: 2 dirs * 8 batches * 8 qchunks * 8 splits = 1024 blocks
// dist(q,t) = |q|^2 + |t|^2 - 2 q.t = qn + 2*s,  s = |t|^2/2 - q.t
// partial[((dir*B+b)*SPLITS+split)*NPTS + q] = qn + 2*min_{t in split} s
__global__ __launch_bounds__(THREADS) void chamfer_kernel(
    const float* __restrict__ pred, const float* __restrict__ targ,
    float* __restrict__ partial) {
  int id = blockIdx.x;
  int split  = id & 7;
  int qchunk = (id >> 3) & 7;
  int b      = (id >> 6) & 7;
  int dir    = id >> 9;
  const float* qp = dir ? targ : pred;
  const float* rp = dir ? pred : targ;

  __shared__ float4 refs[REFS];   // x, y, z, 0.5*|t|^2  (8 KB)
  int tid = threadIdx.x;
  const float* rb = rp + ((size_t)b * NPTS + (size_t)split * REFS) * 3;
  for (int i = tid; i < REFS; i += THREADS) {
    float x = rb[i * 3 + 0], y = rb[i * 3 + 1], z = rb[i * 3 + 2];
    refs[i] = make_float4(x, y, z, 0.5f * (x * x + y * y + z * z));
  }
  __syncthreads();

  int q0 = qchunk * QPB + tid;
  int q1 = q0 + 256;
  const float* qb = qp + (size_t)b * NPTS * 3;
  float q0x = qb[q0 * 3], q0y = qb[q0 * 3 + 1], q0z = qb[q0 * 3 + 2];
  float q1x = qb[q1 * 3], q1y = qb[q1 * 3 + 1], q1z = qb[q1 * 3 + 2];

  float vmin0 = 3.4e38f, vmin1 = 3.4e38f;
#pragma unroll 8
  for (int j = 0; j < REFS; ++j) {
    float4 t = refs[j];
    float s0 = fmaf(-q0x, t.x, fmaf(-q0y, t.y, fmaf(-q0z, t.z, t.w)));
    float s1 = fmaf(-q1x, t.x, fmaf(-q1y, t.y, fmaf(-q1z, t.z, t.w)));
    vmin0 = fminf(vmin0, s0);
    vmin1 = fminf(vmin1, s1);
  }
  float qn0 = q0x * q0x + q0y * q0y + q0z * q0z;
  float qn1 = q1x * q1x + q1y * q1y + q1z * q1z;
  size_t base = (((size_t)dir * B + b) * SPLITS + split) * NPTS;
  partial[base + q0] = fmaf(2.f, vmin0, qn0);
  partial[base + q1] = fmaf(2.f, vmin1, qn1);
}

// -------- K2: min over splits, per-(dir,b,chunk) sums of min and exp ----
// grid: 2 * 8 * 8 = 128 blocks; sums2[id] = {sum_min, sum_soft}
__global__ __launch_bounds__(THREADS) void reduce_kernel(
    const float* __restrict__ partial, float* __restrict__ sums2) {
  int id = blockIdx.x;
  int chunk = id & 7;
  int b   = (id >> 3) & 7;
  int dir = id >> 6;
  int tid = threadIdx.x;
  size_t pb = ((size_t)dir * B + b) * SPLITS * NPTS;

  float s_min = 0.f, s_soft = 0.f;
#pragma unroll
  for (int i = 0; i < 2; ++i) {
    int q = chunk * 512 + i * 256 + tid;
    float m = 3.4e38f;
#pragma unroll
    for (int s = 0; s < SPLITS; ++s)
      m = fminf(m, partial[pb + (size_t)s * NPTS + q]);
    s_min  += m;
    s_soft += __expf(-5000.0f * m);   // 1/(2*sigma^2) = 5000
  }
  // wave (64) then block (4 waves) reduction
  for (int off = 32; off > 0; off >>= 1) {
    s_min  += __shfl_down(s_min,  off);
    s_soft += __shfl_down(s_soft, off);
  }
  __shared__ float red[8];
  int wave = tid >> 6, lane = tid & 63;
  if (lane == 0) { red[wave * 2] = s_min; red[wave * 2 + 1] = s_soft; }
  __syncthreads();
  if (tid == 0) {
    float a = 0.f, c = 0.f;
    for (int w = 0; w < 4; ++w) { a += red[w * 2]; c += red[w * 2 + 1]; }
    sums2[id * 2] = a;
    sums2[id * 2 + 1] = c;
  }
}

// -------- K3: domain classifier MLP (eval mode) + NLL -------------------
// grid: 8 blocks (one per batch row), 256 threads
__global__ __launch_bounds__(THREADS) void mlp_kernel(
    const float* __restrict__ x,
    const float* __restrict__ W1, const float* __restrict__ b1,
    const float* __restrict__ W2, const float* __restrict__ b2,
    const float* __restrict__ W3, const float* __restrict__ b3,
    const int* __restrict__ labels, float* __restrict__ nll) {
  int b = blockIdx.x;
  int tid = threadIdx.x;
  __shared__ float xs[512];
  __shared__ float h1[256];
  __shared__ float h2[128];
  __shared__ float lg[6];
  for (int i = tid; i < 512; i += THREADS) xs[i] = x[b * 512 + i];
  __syncthreads();
  {
    float acc = b1[tid];
#pragma unroll 8
    for (int k = 0; k < 512; ++k) acc = fmaf(xs[k], W1[k * 256 + tid], acc);
    h1[tid] = fmaxf(acc, 0.f);
  }
  __syncthreads();
  if (tid < 128) {
    float acc = b2[tid];
#pragma unroll 8
    for (int k = 0; k < 256; ++k) acc = fmaf(h1[k], W2[k * 128 + tid], acc);
    h2[tid] = fmaxf(acc, 0.f);
  }
  __syncthreads();
  if (tid < 6) {
    float acc = b3[tid];
#pragma unroll 8
    for (int k = 0; k < 128; ++k) acc = fmaf(h2[k], W3[k * 6 + tid], acc);
    lg[tid] = acc;
  }
  __syncthreads();
  if (tid == 0) {
    float mx = lg[0];
    for (int j = 1; j < 6; ++j) mx = fmaxf(mx, lg[j]);
    float se = 0.f;
    for (int j = 0; j < 6; ++j) se += __expf(lg[j] - mx);
    int lab = labels[b];
    nll[b] = -(lg[lab] - mx - __logf(se));
  }
}

// -------- K4: final scalar combine --------------------------------------
__global__ void final_kernel(const float* __restrict__ sums2,
                             const float* __restrict__ nll,
                             const float* __restrict__ w,
                             float* __restrict__ out) {
  if (threadIdx.x != 0) return;
  float chamfer = 0.f, prec = 0.f, rec = 0.f, dsw = 0.f, dom = 0.f;
  for (int b = 0; b < B; ++b) {
    float sa = 0.f, ssa = 0.f, sb = 0.f, ssb = 0.f;
    for (int c = 0; c < 8; ++c) {
      int ia = ((0 * B + b) * 8 + c) * 2;
      int ib = ((1 * B + b) * 8 + c) * 2;
      sa += sums2[ia];  ssa += sums2[ia + 1];
      sb += sums2[ib];  ssb += sums2[ib + 1];
    }
    float ma = sa / 4096.f, mb = sb / 4096.f;
    float p = ssa / 4096.f, r = ssb / 4096.f;
    chamfer += ma + mb;
    prec += p; rec += r;
    float f_i = 2.f * p * r / (p + r + 1e-8f);
    float loss_i = ma + mb + 0.1f * (1.f - f_i);
    dsw += w[b] * loss_i;
    dom += nll[b];
  }
  chamfer *= (1.f / B); prec *= (1.f / B); rec *= (1.f / B);
  dsw *= (1.f / B); dom *= (1.f / B);
  float fscore = 2.f * prec * rec / (prec + rec + 1e-8f);
  float task = chamfer + 0.1f * (1.f - fscore);
  out[0] = 1.0f * task + 0.1f * dom + dsw;
}

extern "C" void kernel_launch(void* const* d_in, const int* in_sizes, int n_in,
                              void* d_out, int out_size, void* d_ws, size_t ws_size,
                              hipStream_t stream) {
  const float* pred   = (const float*)d_in[0];
  const float* targ   = (const float*)d_in[1];
  const float* x      = (const float*)d_in[2];
  const float* wgt    = (const float*)d_in[3];
  const float* W1     = (const float*)d_in[4];
  const float* b1     = (const float*)d_in[5];
  const float* W2     = (const float*)d_in[6];
  const float* b2     = (const float*)d_in[7];
  const float* W3     = (const float*)d_in[8];
  const float* b3     = (const float*)d_in[9];
  const int*   labels = (const int*)d_in[10];
  float* out = (float*)d_out;

  // ws layout: [partial: 2*8*8*4096 floats = 2 MB][sums2: 256 floats][nll: 8 floats]
  char* ws = (char*)d_ws;
  float* partial = (float*)ws;
  float* sums2   = (float*)(ws + (size_t)2 * B * SPLITS * NPTS * sizeof(float));
  float* nll     = sums2 + 256;

  hipLaunchKernelGGL(chamfer_kernel, dim3(1024), dim3(THREADS), 0, stream,
                     pred, targ, partial);
  hipLaunchKernelGGL(reduce_kernel, dim3(128), dim3(THREADS), 0, stream,
                     partial, sums2);
  hipLaunchKernelGGL(mlp_kernel, dim3(B), dim3(THREADS), 0, stream,
                     x, W1, b1, W2, b2, W3, b3, labels, nll);
  hipLaunchKernelGGL(final_kernel, dim3(1), dim3(64), 0, stream,
                     sums2, nll, wgt, out);
}

// Round 2
// 131.638 us; speedup vs baseline: 1.0620x; 1.0620x over previous
//
#include <hip/hip_runtime.h>
#include <math.h>

#define B 8
#define NPTS 4096
#define SPLITS 8        // ref splits per direction
#define REFS 512        // refs per split  (SPLITS*REFS == NPTS)
#define QPT 8           // queries per thread in chamfer
#define THREADS 256

// -------- K1: split-partial chamfer mins --------------------------------
// grid: dir(2) * b(8) * qchunk(2) * split(8) = 256 blocks
// dist(q,t) = |q|^2 + 2*s,  s = |t|^2/2 - q.t
__global__ __launch_bounds__(THREADS) void chamfer_kernel(
    const float* __restrict__ pred, const float* __restrict__ targ,
    float* __restrict__ partial) {
  int id = blockIdx.x;
  int split  = id & 7;
  int qchunk = (id >> 3) & 1;
  int b      = (id >> 4) & 7;
  int dir    = id >> 7;
  const float* qp = dir ? targ : pred;
  const float* rp = dir ? pred : targ;

  __shared__ float4 refs[REFS];   // x, y, z, 0.5*|t|^2  (8 KB)
  int tid = threadIdx.x;
  const float* rb = rp + ((size_t)b * NPTS + (size_t)split * REFS) * 3;
  for (int i = tid; i < REFS; i += THREADS) {
    float x = rb[i * 3 + 0], y = rb[i * 3 + 1], z = rb[i * 3 + 2];
    refs[i] = make_float4(x, y, z, 0.5f * (x * x + y * y + z * z));
  }
  __syncthreads();

  const float* qb = qp + (size_t)b * NPTS * 3;
  int q0 = qchunk * (QPT * THREADS) + tid;
  float qx[QPT], qy[QPT], qz[QPT], vmin[QPT];
#pragma unroll
  for (int i = 0; i < QPT; ++i) {
    int q = q0 + i * THREADS;
    qx[i] = qb[q * 3 + 0];
    qy[i] = qb[q * 3 + 1];
    qz[i] = qb[q * 3 + 2];
    vmin[i] = 3.4e38f;
  }

#pragma unroll 2
  for (int j = 0; j < REFS; j += 2) {
    float4 ta = refs[j];
    float4 tb = refs[j + 1];
#pragma unroll
    for (int i = 0; i < QPT; ++i) {
      float sa = fmaf(-qx[i], ta.x, fmaf(-qy[i], ta.y, fmaf(-qz[i], ta.z, ta.w)));
      float sb = fmaf(-qx[i], tb.x, fmaf(-qy[i], tb.y, fmaf(-qz[i], tb.z, tb.w)));
      vmin[i] = fminf(vmin[i], fminf(sa, sb));   // v_min3_f32
    }
  }

  size_t base = (((size_t)dir * B + b) * SPLITS + split) * NPTS;
#pragma unroll
  for (int i = 0; i < QPT; ++i) {
    float qn = fmaf(qx[i], qx[i], fmaf(qy[i], qy[i], qz[i] * qz[i]));
    partial[base + q0 + i * THREADS] = fmaf(2.f, vmin[i], qn);
  }
}

// -------- K2: min over splits, per-(dir,b,chunk) sums of min and exp ----
// grid: 2 * 8 * 8 = 128 blocks; sums2[id] = {sum_min, sum_soft}
__global__ __launch_bounds__(THREADS) void reduce_kernel(
    const float* __restrict__ partial, float* __restrict__ sums2) {
  int id = blockIdx.x;
  int chunk = id & 7;
  int b   = (id >> 3) & 7;
  int dir = id >> 6;
  int tid = threadIdx.x;
  size_t pb = ((size_t)dir * B + b) * SPLITS * NPTS;

  float s_min = 0.f, s_soft = 0.f;
#pragma unroll
  for (int i = 0; i < 2; ++i) {
    int q = chunk * 512 + i * 256 + tid;
    float m = 3.4e38f;
#pragma unroll
    for (int s = 0; s < SPLITS; ++s)
      m = fminf(m, partial[pb + (size_t)s * NPTS + q]);
    s_min  += m;
    s_soft += __expf(-5000.0f * m);   // 1/(2*sigma^2) = 5000
  }
  for (int off = 32; off > 0; off >>= 1) {
    s_min  += __shfl_down(s_min,  off);
    s_soft += __shfl_down(s_soft, off);
  }
  __shared__ float red[8];
  int wave = tid >> 6, lane = tid & 63;
  if (lane == 0) { red[wave * 2] = s_min; red[wave * 2 + 1] = s_soft; }
  __syncthreads();
  if (tid == 0) {
    float a = 0.f, c = 0.f;
    for (int w = 0; w < 4; ++w) { a += red[w * 2]; c += red[w * 2 + 1]; }
    sums2[id * 2] = a;
    sums2[id * 2 + 1] = c;
  }
}

// -------- K3a: MLP layer 1 partials -------------------------------------
// grid: b(8) * kc(8) = 64 blocks. h1p[(b*8+kc)*256 + j] = sum_{k in chunk} x*W1
__global__ __launch_bounds__(THREADS) void l1_kernel(
    const float* __restrict__ x, const float* __restrict__ W1,
    float* __restrict__ h1p) {
  int b  = blockIdx.x >> 3;
  int kc = blockIdx.x & 7;
  int tid = threadIdx.x;
  __shared__ float xs[64];
  if (tid < 64) xs[tid] = x[b * 512 + kc * 64 + tid];
  __syncthreads();
  float acc = 0.f;
  const float* w = W1 + (size_t)(kc * 64) * 256 + tid;
#pragma unroll 8
  for (int k = 0; k < 64; ++k) acc = fmaf(xs[k], w[k * 256], acc);
  h1p[(b * 8 + kc) * 256 + tid] = acc;
}

// -------- K3b: layer1 finish + layer 2 partials --------------------------
// grid: b(8) * kc(2) = 16 blocks, 128 threads.
// h2p[(b*2+kc)*128 + j] = sum_{k in chunk} relu(h1[b][k]) * W2[k][j]
__global__ __launch_bounds__(128) void l2_kernel(
    const float* __restrict__ h1p, const float* __restrict__ b1,
    const float* __restrict__ W2, float* __restrict__ h2p) {
  int b  = blockIdx.x >> 1;
  int kc = blockIdx.x & 1;
  int tid = threadIdx.x;
  __shared__ float hs[128];
  {
    int k = kc * 128 + tid;
    float a = b1[k];
#pragma unroll
    for (int p = 0; p < 8; ++p) a += h1p[(b * 8 + p) * 256 + k];
    hs[tid] = fmaxf(a, 0.f);
  }
  __syncthreads();
  float acc = 0.f;
  const float* w = W2 + (size_t)(kc * 128) * 128 + tid;
#pragma unroll 8
  for (int k = 0; k < 128; ++k) acc = fmaf(hs[k], w[k * 128], acc);
  h2p[(b * 2 + kc) * 128 + tid] = acc;
}

// -------- K4: layer2 finish + layer 3 + softmax/NLL + final combine -----
// 1 block, 256 threads
__global__ __launch_bounds__(THREADS) void final_kernel(
    const float* __restrict__ h2p, const float* __restrict__ b2,
    const float* __restrict__ W3, const float* __restrict__ b3,
    const int* __restrict__ labels, const float* __restrict__ sums2,
    const float* __restrict__ w, float* __restrict__ out) {
  int tid = threadIdx.x;
  __shared__ float h2s[8 * 128];
  __shared__ float lg[48];
  __shared__ float nlls[8];
  __shared__ float sred_min[16];   // [dir*8+b]
  __shared__ float sred_soft[16];

  for (int i = tid; i < 1024; i += THREADS) {
    int b = i >> 7, j = i & 127;
    float a = b2[j] + h2p[(b * 2 + 0) * 128 + j] + h2p[(b * 2 + 1) * 128 + j];
    h2s[i] = fmaxf(a, 0.f);
  }
  // waves 1,2: reduce sums2 (128 entries of {min,soft}) over chunk dim
  if (tid >= 64 && tid < 192) {
    int t = tid - 64;                    // t = (dir*8+b)*8 + c
    float mn = sums2[2 * t], sf = sums2[2 * t + 1];
    for (int off = 4; off > 0; off >>= 1) {
      mn += __shfl_down(mn, off, 8);
      sf += __shfl_down(sf, off, 8);
    }
    if ((t & 7) == 0) { sred_min[t >> 3] = mn; sred_soft[t >> 3] = sf; }
  }
  __syncthreads();
  if (tid < 48) {
    int b = tid / 6, d = tid % 6;
    float acc = b3[d];
#pragma unroll 8
    for (int k = 0; k < 128; ++k) acc = fmaf(h2s[b * 128 + k], W3[k * 6 + d], acc);
    lg[tid] = acc;
  }
  __syncthreads();
  if (tid < 8) {
    int b = tid;
    float mx = lg[b * 6];
    for (int d = 1; d < 6; ++d) mx = fmaxf(mx, lg[b * 6 + d]);
    float se = 0.f;
    for (int d = 0; d < 6; ++d) se += __expf(lg[b * 6 + d] - mx);
    int lab = labels[b];
    nlls[b] = -(lg[b * 6 + lab] - mx - __logf(se));
  }
  __syncthreads();
  if (tid == 0) {
    float chamfer = 0.f, prec = 0.f, rec = 0.f, dsw = 0.f, dom = 0.f;
    for (int b = 0; b < B; ++b) {
      float sa = sred_min[b],      ssa = sred_soft[b];
      float sb = sred_min[8 + b],  ssb = sred_soft[8 + b];
      float ma = sa / 4096.f, mb = sb / 4096.f;
      float p = ssa / 4096.f, r = ssb / 4096.f;
      chamfer += ma + mb;
      prec += p; rec += r;
      float f_i = 2.f * p * r / (p + r + 1e-8f);
      float loss_i = ma + mb + 0.1f * (1.f - f_i);
      dsw += w[b] * loss_i;
      dom += nlls[b];
    }
    chamfer *= (1.f / B); prec *= (1.f / B); rec *= (1.f / B);
    dsw *= (1.f / B); dom *= (1.f / B);
    float fscore = 2.f * prec * rec / (prec + rec + 1e-8f);
    float task = chamfer + 0.1f * (1.f - fscore);
    out[0] = 1.0f * task + 0.1f * dom + dsw;
  }
}

extern "C" void kernel_launch(void* const* d_in, const int* in_sizes, int n_in,
                              void* d_out, int out_size, void* d_ws, size_t ws_size,
                              hipStream_t stream) {
  const float* pred   = (const float*)d_in[0];
  const float* targ   = (const float*)d_in[1];
  const float* x      = (const float*)d_in[2];
  const float* wgt    = (const float*)d_in[3];
  const float* W1     = (const float*)d_in[4];
  const float* b1     = (const float*)d_in[5];
  const float* W2     = (const float*)d_in[6];
  const float* b2     = (const float*)d_in[7];
  const float* W3     = (const float*)d_in[8];
  const float* b3     = (const float*)d_in[9];
  const int*   labels = (const int*)d_in[10];
  float* out = (float*)d_out;

  // ws layout: [partial 2MB][sums2 256f][h1p 16384f][h2p 2048f]
  char* ws = (char*)d_ws;
  float* partial = (float*)ws;
  float* sums2   = (float*)(ws + (size_t)2 * B * SPLITS * NPTS * sizeof(float));
  float* h1p     = sums2 + 256;
  float* h2p     = h1p + 8 * 8 * 256;

  hipLaunchKernelGGL(chamfer_kernel, dim3(256), dim3(THREADS), 0, stream,
                     pred, targ, partial);
  hipLaunchKernelGGL(reduce_kernel, dim3(128), dim3(THREADS), 0, stream,
                     partial, sums2);
  hipLaunchKernelGGL(l1_kernel, dim3(64), dim3(THREADS), 0, stream,
                     x, W1, h1p);
  hipLaunchKernelGGL(l2_kernel, dim3(16), dim3(128), 0, stream,
                     h1p, b1, W2, h2p);
  hipLaunchKernelGGL(final_kernel, dim3(1), dim3(THREADS), 0, stream,
                     h2p, b2, W3, b3, labels, sums2, wgt, out);
}